// Round 5
// baseline (266.199 us; speedup 1.0000x reference)
//
#include <hip/hip_runtime.h>
#include <hip/hip_bf16.h>

// Problem dims (fixed by the reference)
#define NTOK   (256 * 512)     // B*S tokens
#define N_USER 7442

using bf16 = __hip_bfloat16;
typedef float f32x4 __attribute__((ext_vector_type(4)));  // native vec for nontemporal builtin

static __device__ __forceinline__ float4 ld4(const float* p) {
    return *reinterpret_cast<const float4*>(p);
}
// bf16 pair unpack (little-endian: element at lower address = low 16 bits)
static __device__ __forceinline__ float bfl(unsigned u) {
    union { unsigned u; float f; } c; c.u = u << 16; return c.f;
}
static __device__ __forceinline__ float bfh(unsigned u) {
    union { unsigned u; float f; } c; c.u = u & 0xFFFF0000u; return c.f;
}
static __device__ __forceinline__ void st_nt4(float* p, float x, float y, float z, float w) {
    f32x4 v; v.x = x; v.y = y; v.z = z; v.w = w;
    __builtin_nontemporal_store(v, reinterpret_cast<f32x4*>(p));
}

// ---- precompute geometry ----
// Graph blocks first (longest), then item, tag, int. 16 rows/block everywhere.
#define RG 16
#define RS 16
#define NB_TESTG 94           // ceil(1500/16)
#define NB_ITEM  591          // ceil(9455/16)
#define NB_TAG   58           // ceil(913/16)
#define NB_INT   1            // 3 rows
#define NB_TOTAL (NB_TESTG + NB_ITEM + NB_TAG + NB_INT)

// Folded tables:
//   Pitem  = emb_item @ W2                       (bf16, 9455x256)
//   Ptag   = emb_tag  @ W3                       (bf16,  913x256)
//   Pint   = emb_int  @ W0                       (bf16,    3x256)
//   Ptestg = emb_test @ W1 + (graph_rows @ graph_W) @ W4 + comb_b + graph_b @ W4
// E-row reads are wave-uniform -> direct global broadcast loads (no LDS staging).
// LDS only holds the graph-path intermediate (transpose), 16 KB.
__global__ __launch_bounds__(256) void precompute_kernel(
    const float* __restrict__ emb_int,  const float* __restrict__ emb_test,
    const float* __restrict__ emb_item, const float* __restrict__ emb_tag,
    const float* __restrict__ graph_tab, const float* __restrict__ graph_W,
    const float* __restrict__ graph_b,
    const float* __restrict__ comb_W,   const float* __restrict__ comb_b,
    bf16* __restrict__ Pint, bf16* __restrict__ Ptestg,
    bf16* __restrict__ Pitem, bf16* __restrict__ Ptag) {
    __shared__ float ldsT[RG * 256];   // 16 KB, graph path only
    const int tid = threadIdx.x;
    const int b   = blockIdx.x;

    const float* W0 = comb_W;              // interaction
    const float* W1 = comb_W + 256 * 256;  // testId
    const float* W2 = comb_W + 512 * 256;  // itemId
    const float* W3 = comb_W + 768 * 256;  // tag
    const float* W4 = comb_W + 1024 * 256; // graph

    if (b < NB_TESTG) {
        // -------- graph+test fused path --------
        const int row0 = b * RG;
        const int nr   = min(RG, 1500 - row0);

        // B: tmp = graph_rows @ graph_W   (K = 512), rows read uniform from global
        float acc[RG];
        #pragma unroll
        for (int r = 0; r < RG; ++r) acc[r] = 0.f;
        for (int m = 0; m < 512; m += 4) {
            const float w0 = graph_W[(m + 0) * 256 + tid];
            const float w1 = graph_W[(m + 1) * 256 + tid];
            const float w2 = graph_W[(m + 2) * 256 + tid];
            const float w3 = graph_W[(m + 3) * 256 + tid];
            #pragma unroll
            for (int r = 0; r < RG; ++r) {
                const int row = N_USER - 1 + row0 + min(r, nr - 1);
                const float4 e = ld4(graph_tab + (size_t)row * 512 + m);
                acc[r] += e.x * w0 + e.y * w1 + e.z * w2 + e.w * w3;
            }
        }
        #pragma unroll
        for (int r = 0; r < RG; ++r) ldsT[r * 256 + tid] = acc[r];
        __syncthreads();

        // C: P = tmp @ W4 + test @ W1 (+ graph_b @ W4 + comb_b)
        float acc2[RG];
        float bacc = 0.f;
        #pragma unroll
        for (int r = 0; r < RG; ++r) acc2[r] = 0.f;
        for (int m = 0; m < 256; m += 4) {
            const float w40 = W4[(m + 0) * 256 + tid];
            const float w41 = W4[(m + 1) * 256 + tid];
            const float w42 = W4[(m + 2) * 256 + tid];
            const float w43 = W4[(m + 3) * 256 + tid];
            const float w10 = W1[(m + 0) * 256 + tid];
            const float w11 = W1[(m + 1) * 256 + tid];
            const float w12 = W1[(m + 2) * 256 + tid];
            const float w13 = W1[(m + 3) * 256 + tid];
            bacc += graph_b[m + 0] * w40 + graph_b[m + 1] * w41 +
                    graph_b[m + 2] * w42 + graph_b[m + 3] * w43;
            #pragma unroll
            for (int r = 0; r < RG; ++r) {
                const int row = row0 + min(r, nr - 1);
                const float4 tv = ld4(&ldsT[r * 256 + m]);
                const float4 ev = ld4(emb_test + (size_t)row * 256 + m);
                acc2[r] += tv.x * w40 + tv.y * w41 + tv.z * w42 + tv.w * w43 +
                           ev.x * w10 + ev.y * w11 + ev.z * w12 + ev.w * w13;
            }
        }
        const float bias = bacc + comb_b[tid];
        for (int r = 0; r < nr; ++r)
            Ptestg[(size_t)(row0 + r) * 256 + tid] = __float2bfloat16(acc2[r] + bias);
    } else {
        // -------- simple path: P = E @ W, K = 256 --------
        const float* E; const float* W; bf16* P; int row0, R;
        const int sb = b - NB_TESTG;
        if (sb < NB_ITEM)               { E = emb_item; W = W2; P = Pitem; row0 = sb * RS;             R = 9455; }
        else if (sb < NB_ITEM + NB_TAG) { E = emb_tag;  W = W3; P = Ptag;  row0 = (sb - NB_ITEM) * RS; R = 913;  }
        else                            { E = emb_int;  W = W0; P = Pint;  row0 = 0;                   R = 3;    }
        const int nr = min(RS, R - row0);

        float acc[RS];
        #pragma unroll
        for (int r = 0; r < RS; ++r) acc[r] = 0.f;
        for (int m = 0; m < 256; m += 4) {
            const float w0 = W[(m + 0) * 256 + tid];
            const float w1 = W[(m + 1) * 256 + tid];
            const float w2 = W[(m + 2) * 256 + tid];
            const float w3 = W[(m + 3) * 256 + tid];
            #pragma unroll
            for (int r = 0; r < RS; ++r) {
                const int row = row0 + min(r, nr - 1);   // clamp (uniform), write-guarded below
                const float4 e = ld4(E + (size_t)row * 256 + m);
                acc[r] += e.x * w0 + e.y * w1 + e.z * w2 + e.w * w3;
            }
        }
        for (int r = 0; r < nr; ++r)
            P[(size_t)(row0 + r) * 256 + tid] = __float2bfloat16(acc[r]);
    }
}

// 2048 blocks x 256 threads; each wave handles 16 consecutive tokens.
// Wave-invariant params hoisted into registers before the token loop.
__global__ __launch_bounds__(256) void main_kernel(
    const int* __restrict__ testId, const int* __restrict__ itemId,
    const int* __restrict__ tagId,  const int* __restrict__ inter,
    const float* __restrict__ cont_feats,
    const bf16* __restrict__ Pint, const bf16* __restrict__ Ptestg,
    const bf16* __restrict__ Pitem, const bf16* __restrict__ Ptag,
    const float* __restrict__ comb_g, const float* __restrict__ comb_beta,
    const float* __restrict__ cont_W, const float* __restrict__ cont_b,
    const float* __restrict__ cont_g, const float* __restrict__ cont_beta,
    float* __restrict__ out) {
    const int wid  = blockIdx.x * 4 + (threadIdx.x >> 6);
    const int lane = threadIdx.x & 63;
    const int c    = lane * 4;

    // hoisted wave-invariant parameters (8 x float4 = 32 VGPRs)
    const float4 g4  = ld4(comb_g + c);
    const float4 b4  = ld4(comb_beta + c);
    const float4 w0  = ld4(cont_W + 0 * 256 + c);
    const float4 w1  = ld4(cont_W + 1 * 256 + c);
    const float4 w2  = ld4(cont_W + 2 * 256 + c);
    const float4 cb  = ld4(cont_b + c);
    const float4 g42 = ld4(cont_g + c);
    const float4 b42 = ld4(cont_beta + c);

    const int t0 = wid * 16;
    #pragma unroll 2
    for (int k = 0; k < 16; ++k) {
        const int t = t0 + k;
        const int ti = testId[t];
        const int ii = itemId[t];
        const int tg = tagId[t];
        const int iv = inter[t];

        // ---- cate path: 4 bf16 gathers (Ptestg carries bias) ----
        const uint2 u0 = *reinterpret_cast<const uint2*>(Pint   + iv * 256 + c);
        const uint2 u1 = *reinterpret_cast<const uint2*>(Ptestg + (size_t)ti * 256 + c);
        const uint2 u2 = *reinterpret_cast<const uint2*>(Pitem  + (size_t)ii * 256 + c);
        const uint2 u3 = *reinterpret_cast<const uint2*>(Ptag   + (size_t)tg * 256 + c);
        float vx = bfl(u0.x) + bfl(u1.x) + bfl(u2.x) + bfl(u3.x);
        float vy = bfh(u0.x) + bfh(u1.x) + bfh(u2.x) + bfh(u3.x);
        float vz = bfl(u0.y) + bfl(u1.y) + bfl(u2.y) + bfl(u3.y);
        float vw = bfh(u0.y) + bfh(u1.y) + bfh(u2.y) + bfh(u3.y);

        float s  = vx + vy + vz + vw;
        float ss = vx * vx + vy * vy + vz * vz + vw * vw;
        #pragma unroll
        for (int off = 32; off >= 1; off >>= 1) {
            s  += __shfl_xor(s,  off, 64);
            ss += __shfl_xor(ss, off, 64);
        }
        const float mu  = s * (1.f / 256.f);
        const float var = ss * (1.f / 256.f) - mu * mu;
        const float inv = rsqrtf(var + 1e-5f);

        float* po = out + (size_t)t * 512;
        st_nt4(po + c,
               (vx - mu) * inv * g4.x + b4.x,
               (vy - mu) * inv * g4.y + b4.y,
               (vz - mu) * inv * g4.z + b4.z,
               (vw - mu) * inv * g4.w + b4.w);

        // ---- cont path: [3] @ cont_W[3][256] + LN ----
        const float c0 = cont_feats[t * 3 + 0];
        const float c1 = cont_feats[t * 3 + 1];
        const float c2 = cont_feats[t * 3 + 2];
        float ux = c0 * w0.x + c1 * w1.x + c2 * w2.x + cb.x;
        float uy = c0 * w0.y + c1 * w1.y + c2 * w2.y + cb.y;
        float uz = c0 * w0.z + c1 * w1.z + c2 * w2.z + cb.z;
        float uw = c0 * w0.w + c1 * w1.w + c2 * w2.w + cb.w;

        float s2  = ux + uy + uz + uw;
        float ss2 = ux * ux + uy * uy + uz * uz + uw * uw;
        #pragma unroll
        for (int off = 32; off >= 1; off >>= 1) {
            s2  += __shfl_xor(s2,  off, 64);
            ss2 += __shfl_xor(ss2, off, 64);
        }
        const float mu2  = s2 * (1.f / 256.f);
        const float var2 = ss2 * (1.f / 256.f) - mu2 * mu2;
        const float inv2 = rsqrtf(var2 + 1e-5f);

        st_nt4(po + 256 + c,
               (ux - mu2) * inv2 * g42.x + b42.x,
               (uy - mu2) * inv2 * g42.y + b42.y,
               (uz - mu2) * inv2 * g42.z + b42.z,
               (uw - mu2) * inv2 * g42.w + b42.w);
    }
}

extern "C" void kernel_launch(void* const* d_in, const int* in_sizes, int n_in,
                              void* d_out, int out_size, void* d_ws, size_t ws_size,
                              hipStream_t stream) {
    const int*   testId     = (const int*)d_in[0];
    const int*   itemId     = (const int*)d_in[1];
    const int*   tagId      = (const int*)d_in[2];
    const float* cont_feats = (const float*)d_in[3];
    const int*   inter      = (const int*)d_in[4];
    const float* emb_int    = (const float*)d_in[5];
    const float* emb_test   = (const float*)d_in[6];
    const float* emb_item   = (const float*)d_in[7];
    const float* emb_tag    = (const float*)d_in[8];
    const float* graph_tab  = (const float*)d_in[9];
    const float* graph_W    = (const float*)d_in[10];
    const float* graph_b    = (const float*)d_in[11];
    const float* comb_W     = (const float*)d_in[12];
    const float* comb_b     = (const float*)d_in[13];
    const float* comb_g     = (const float*)d_in[14];
    const float* comb_beta  = (const float*)d_in[15];
    const float* cont_W     = (const float*)d_in[16];
    const float* cont_b     = (const float*)d_in[17];
    const float* cont_g     = (const float*)d_in[18];
    const float* cont_beta  = (const float*)d_in[19];
    float* out              = (float*)d_out;

    // Workspace: bf16 tables, each offset 256-element aligned. ~6.1 MB total.
    bf16* ws     = (bf16*)d_ws;
    bf16* Pitem  = ws;                         // 9455*256
    bf16* Ptestg = Pitem  + 9455 * 256;        // 1500*256 (test + graph + bias fused)
    bf16* Ptag   = Ptestg + 1500 * 256;        //  913*256
    bf16* Pint   = Ptag   +  913 * 256;        //    3*256

    precompute_kernel<<<NB_TOTAL, 256, 0, stream>>>(
        emb_int, emb_test, emb_item, emb_tag, graph_tab, graph_W, graph_b,
        comb_W, comb_b, Pint, Ptestg, Pitem, Ptag);

    // 2048 blocks x 4 waves; 16 tokens per wave.
    main_kernel<<<NTOK / (4 * 16), 256, 0, stream>>>(
        testId, itemId, tagId, inter, cont_feats,
        Pint, Ptestg, Pitem, Ptag,
        comb_g, comb_beta, cont_W, cont_b, cont_g, cont_beta, out);
}

// Round 6
// 154.685 us; speedup vs baseline: 1.7209x; 1.7209x over previous
//
#include <hip/hip_runtime.h>
#include <hip/hip_bf16.h>

// Problem dims (fixed by the reference)
#define NTOK   (256 * 512)     // B*S tokens
#define N_USER 7442

using bf16 = __hip_bfloat16;
typedef float f32x4 __attribute__((ext_vector_type(4)));  // native vec for nontemporal builtin

static __device__ __forceinline__ float4 ld4(const float* p) {
    return *reinterpret_cast<const float4*>(p);
}
// bf16 pair unpack (little-endian: element at lower address = low 16 bits)
static __device__ __forceinline__ float bfl(unsigned u) {
    union { unsigned u; float f; } c; c.u = u << 16; return c.f;
}
static __device__ __forceinline__ float bfh(unsigned u) {
    union { unsigned u; float f; } c; c.u = u & 0xFFFF0000u; return c.f;
}
static __device__ __forceinline__ void st_nt4(float* p, float x, float y, float z, float w) {
    f32x4 v; v.x = x; v.y = y; v.z = z; v.w = w;
    __builtin_nontemporal_store(v, reinterpret_cast<f32x4*>(p));
}

// ---- precompute geometry ----
// Graph blocks first (longest). LDS staged, 32 KB everywhere -> 5 blocks/CU,
// all 420 blocks resident at once (420 < 256*5).
#define RS 32                 // rows/block, simple path (K=256)
#define RG 16                 // rows/block, graph-fused path
#define NB_TESTG 94           // ceil(1500/16)
#define NB_ITEM  296          // ceil(9455/32)
#define NB_TAG   29           // ceil(913/32)
#define NB_INT   1            // 3 rows
#define NB_TOTAL (NB_TESTG + NB_ITEM + NB_TAG + NB_INT)

// Folded tables:
//   Pitem  = emb_item @ W2                       (bf16, 9455x256)
//   Ptag   = emb_tag  @ W3                       (bf16,  913x256)
//   Pint   = emb_int  @ W0                       (bf16,    3x256)
//   Ptestg = emb_test @ W1 + (graph_rows @ graph_W) @ W4 + comb_b + graph_b @ W4
__global__ __launch_bounds__(256) void precompute_kernel(
    const float* __restrict__ emb_int,  const float* __restrict__ emb_test,
    const float* __restrict__ emb_item, const float* __restrict__ emb_tag,
    const float* __restrict__ graph_tab, const float* __restrict__ graph_W,
    const float* __restrict__ graph_b,
    const float* __restrict__ comb_W,   const float* __restrict__ comb_b,
    bf16* __restrict__ Pint, bf16* __restrict__ Ptestg,
    bf16* __restrict__ Pitem, bf16* __restrict__ Ptag) {
    __shared__ float lds[8192];   // 32 KB
    const int tid = threadIdx.x;
    const int b   = blockIdx.x;

    const float* W0 = comb_W;              // interaction
    const float* W1 = comb_W + 256 * 256;  // testId
    const float* W2 = comb_W + 512 * 256;  // itemId
    const float* W3 = comb_W + 768 * 256;  // tag
    const float* W4 = comb_W + 1024 * 256; // graph

    if (b < NB_TESTG) {
        // -------- graph+test fused path --------
        const int row0 = b * RG;
        const int nr   = min(RG, 1500 - row0);

        // A: stage graph rows (16 x 512 f32 = 32 KB)
        for (int i = tid; i < nr * 512; i += 256) {
            const int r = i >> 9, m = i & 511;
            lds[r * 512 + m] = graph_tab[(size_t)(N_USER - 1 + row0 + r) * 512 + m];
        }
        __syncthreads();

        // B: tmp = rows @ graph_W   (K = 512)
        float acc[RG];
        #pragma unroll
        for (int r = 0; r < RG; ++r) acc[r] = 0.f;
        #pragma unroll 2
        for (int m = 0; m < 512; m += 4) {
            const float w0 = graph_W[(m + 0) * 256 + tid];
            const float w1 = graph_W[(m + 1) * 256 + tid];
            const float w2 = graph_W[(m + 2) * 256 + tid];
            const float w3 = graph_W[(m + 3) * 256 + tid];
            #pragma unroll
            for (int r = 0; r < RG; ++r) {
                const float4 e = ld4(&lds[r * 512 + m]);
                acc[r] += e.x * w0 + e.y * w1 + e.z * w2 + e.w * w3;
            }
        }
        __syncthreads();   // all phase-B reads done before overwrite

        // tmp -> lds[0..4095]; emb_test rows -> lds[4096..8191]
        #pragma unroll
        for (int r = 0; r < RG; ++r) lds[r * 256 + tid] = acc[r];
        for (int i = tid; i < nr * 256; i += 256) {
            const int r = i >> 8, m = i & 255;
            lds[4096 + r * 256 + m] = emb_test[(size_t)(row0 + r) * 256 + m];
        }
        __syncthreads();

        // C: P = tmp @ W4 + test @ W1 (+ graph_b @ W4 + comb_b)
        float acc2[RG];
        float bacc = 0.f;
        #pragma unroll
        for (int r = 0; r < RG; ++r) acc2[r] = 0.f;
        #pragma unroll 2
        for (int m = 0; m < 256; m += 4) {
            const float w40 = W4[(m + 0) * 256 + tid];
            const float w41 = W4[(m + 1) * 256 + tid];
            const float w42 = W4[(m + 2) * 256 + tid];
            const float w43 = W4[(m + 3) * 256 + tid];
            const float w10 = W1[(m + 0) * 256 + tid];
            const float w11 = W1[(m + 1) * 256 + tid];
            const float w12 = W1[(m + 2) * 256 + tid];
            const float w13 = W1[(m + 3) * 256 + tid];
            bacc += graph_b[m + 0] * w40 + graph_b[m + 1] * w41 +
                    graph_b[m + 2] * w42 + graph_b[m + 3] * w43;
            #pragma unroll
            for (int r = 0; r < RG; ++r) {
                const float4 tv = ld4(&lds[r * 256 + m]);
                const float4 ev = ld4(&lds[4096 + r * 256 + m]);
                acc2[r] += tv.x * w40 + tv.y * w41 + tv.z * w42 + tv.w * w43 +
                           ev.x * w10 + ev.y * w11 + ev.z * w12 + ev.w * w13;
            }
        }
        const float bias = bacc + comb_b[tid];
        for (int r = 0; r < nr; ++r)
            Ptestg[(size_t)(row0 + r) * 256 + tid] = __float2bfloat16(acc2[r] + bias);
    } else {
        // -------- simple path: P = E @ W, K = 256, rows staged in LDS --------
        const float* E; const float* W; bf16* P; int row0, R;
        const int sb = b - NB_TESTG;
        if (sb < NB_ITEM)               { E = emb_item; W = W2; P = Pitem; row0 = sb * RS;             R = 9455; }
        else if (sb < NB_ITEM + NB_TAG) { E = emb_tag;  W = W3; P = Ptag;  row0 = (sb - NB_ITEM) * RS; R = 913;  }
        else                            { E = emb_int;  W = W0; P = Pint;  row0 = 0;                   R = 3;    }
        const int nr = min(RS, R - row0);

        for (int i = tid; i < nr * 256; i += 256) {
            const int r = i >> 8, m = i & 255;
            lds[r * 256 + m] = E[(size_t)(row0 + r) * 256 + m];
        }
        __syncthreads();

        float acc[RS];
        #pragma unroll
        for (int r = 0; r < RS; ++r) acc[r] = 0.f;
        #pragma unroll 2
        for (int m = 0; m < 256; m += 4) {
            const float w0 = W[(m + 0) * 256 + tid];
            const float w1 = W[(m + 1) * 256 + tid];
            const float w2 = W[(m + 2) * 256 + tid];
            const float w3 = W[(m + 3) * 256 + tid];
            #pragma unroll
            for (int r = 0; r < RS; ++r) {
                const float4 e = ld4(&lds[r * 256 + m]);
                acc[r] += e.x * w0 + e.y * w1 + e.z * w2 + e.w * w3;
            }
        }
        for (int r = 0; r < nr; ++r)
            P[(size_t)(row0 + r) * 256 + tid] = __float2bfloat16(acc[r]);
    }
}

// 2048 blocks x 256 threads; each wave handles 16 consecutive tokens.
// Wave-invariant params hoisted into registers before the token loop.
__global__ __launch_bounds__(256) void main_kernel(
    const int* __restrict__ testId, const int* __restrict__ itemId,
    const int* __restrict__ tagId,  const int* __restrict__ inter,
    const float* __restrict__ cont_feats,
    const bf16* __restrict__ Pint, const bf16* __restrict__ Ptestg,
    const bf16* __restrict__ Pitem, const bf16* __restrict__ Ptag,
    const float* __restrict__ comb_g, const float* __restrict__ comb_beta,
    const float* __restrict__ cont_W, const float* __restrict__ cont_b,
    const float* __restrict__ cont_g, const float* __restrict__ cont_beta,
    float* __restrict__ out) {
    const int wid  = blockIdx.x * 4 + (threadIdx.x >> 6);
    const int lane = threadIdx.x & 63;
    const int c    = lane * 4;

    // hoisted wave-invariant parameters (8 x float4 = 32 VGPRs)
    const float4 g4  = ld4(comb_g + c);
    const float4 b4  = ld4(comb_beta + c);
    const float4 w0  = ld4(cont_W + 0 * 256 + c);
    const float4 w1  = ld4(cont_W + 1 * 256 + c);
    const float4 w2  = ld4(cont_W + 2 * 256 + c);
    const float4 cb  = ld4(cont_b + c);
    const float4 g42 = ld4(cont_g + c);
    const float4 b42 = ld4(cont_beta + c);

    const int t0 = wid * 16;
    #pragma unroll 2
    for (int k = 0; k < 16; ++k) {
        const int t = t0 + k;
        const int ti = testId[t];
        const int ii = itemId[t];
        const int tg = tagId[t];
        const int iv = inter[t];

        // ---- cate path: 4 bf16 gathers (Ptestg carries bias) ----
        const uint2 u0 = *reinterpret_cast<const uint2*>(Pint   + iv * 256 + c);
        const uint2 u1 = *reinterpret_cast<const uint2*>(Ptestg + (size_t)ti * 256 + c);
        const uint2 u2 = *reinterpret_cast<const uint2*>(Pitem  + (size_t)ii * 256 + c);
        const uint2 u3 = *reinterpret_cast<const uint2*>(Ptag   + (size_t)tg * 256 + c);
        float vx = bfl(u0.x) + bfl(u1.x) + bfl(u2.x) + bfl(u3.x);
        float vy = bfh(u0.x) + bfh(u1.x) + bfh(u2.x) + bfh(u3.x);
        float vz = bfl(u0.y) + bfl(u1.y) + bfl(u2.y) + bfl(u3.y);
        float vw = bfh(u0.y) + bfh(u1.y) + bfh(u2.y) + bfh(u3.y);

        float s  = vx + vy + vz + vw;
        float ss = vx * vx + vy * vy + vz * vz + vw * vw;
        #pragma unroll
        for (int off = 32; off >= 1; off >>= 1) {
            s  += __shfl_xor(s,  off, 64);
            ss += __shfl_xor(ss, off, 64);
        }
        const float mu  = s * (1.f / 256.f);
        const float var = ss * (1.f / 256.f) - mu * mu;
        const float inv = rsqrtf(var + 1e-5f);

        float* po = out + (size_t)t * 512;
        st_nt4(po + c,
               (vx - mu) * inv * g4.x + b4.x,
               (vy - mu) * inv * g4.y + b4.y,
               (vz - mu) * inv * g4.z + b4.z,
               (vw - mu) * inv * g4.w + b4.w);

        // ---- cont path: [3] @ cont_W[3][256] + LN ----
        const float c0 = cont_feats[t * 3 + 0];
        const float c1 = cont_feats[t * 3 + 1];
        const float c2 = cont_feats[t * 3 + 2];
        float ux = c0 * w0.x + c1 * w1.x + c2 * w2.x + cb.x;
        float uy = c0 * w0.y + c1 * w1.y + c2 * w2.y + cb.y;
        float uz = c0 * w0.z + c1 * w1.z + c2 * w2.z + cb.z;
        float uw = c0 * w0.w + c1 * w1.w + c2 * w2.w + cb.w;

        float s2  = ux + uy + uz + uw;
        float ss2 = ux * ux + uy * uy + uz * uz + uw * uw;
        #pragma unroll
        for (int off = 32; off >= 1; off >>= 1) {
            s2  += __shfl_xor(s2,  off, 64);
            ss2 += __shfl_xor(ss2, off, 64);
        }
        const float mu2  = s2 * (1.f / 256.f);
        const float var2 = ss2 * (1.f / 256.f) - mu2 * mu2;
        const float inv2 = rsqrtf(var2 + 1e-5f);

        st_nt4(po + 256 + c,
               (ux - mu2) * inv2 * g42.x + b42.x,
               (uy - mu2) * inv2 * g42.y + b42.y,
               (uz - mu2) * inv2 * g42.z + b42.z,
               (uw - mu2) * inv2 * g42.w + b42.w);
    }
}

extern "C" void kernel_launch(void* const* d_in, const int* in_sizes, int n_in,
                              void* d_out, int out_size, void* d_ws, size_t ws_size,
                              hipStream_t stream) {
    const int*   testId     = (const int*)d_in[0];
    const int*   itemId     = (const int*)d_in[1];
    const int*   tagId      = (const int*)d_in[2];
    const float* cont_feats = (const float*)d_in[3];
    const int*   inter      = (const int*)d_in[4];
    const float* emb_int    = (const float*)d_in[5];
    const float* emb_test   = (const float*)d_in[6];
    const float* emb_item   = (const float*)d_in[7];
    const float* emb_tag    = (const float*)d_in[8];
    const float* graph_tab  = (const float*)d_in[9];
    const float* graph_W    = (const float*)d_in[10];
    const float* graph_b    = (const float*)d_in[11];
    const float* comb_W     = (const float*)d_in[12];
    const float* comb_b     = (const float*)d_in[13];
    const float* comb_g     = (const float*)d_in[14];
    const float* comb_beta  = (const float*)d_in[15];
    const float* cont_W     = (const float*)d_in[16];
    const float* cont_b     = (const float*)d_in[17];
    const float* cont_g     = (const float*)d_in[18];
    const float* cont_beta  = (const float*)d_in[19];
    float* out              = (float*)d_out;

    // Workspace: bf16 tables, each offset 256-element aligned. ~6.1 MB total.
    bf16* ws     = (bf16*)d_ws;
    bf16* Pitem  = ws;                         // 9455*256
    bf16* Ptestg = Pitem  + 9455 * 256;        // 1500*256 (test + graph + bias fused)
    bf16* Ptag   = Ptestg + 1500 * 256;        //  913*256
    bf16* Pint   = Ptag   +  913 * 256;        //    3*256

    precompute_kernel<<<NB_TOTAL, 256, 0, stream>>>(
        emb_int, emb_test, emb_item, emb_tag, graph_tab, graph_W, graph_b,
        comb_W, comb_b, Pint, Ptestg, Pitem, Ptag);

    // 2048 blocks x 4 waves; 16 tokens per wave.
    main_kernel<<<NTOK / (4 * 16), 256, 0, stream>>>(
        testId, itemId, tagId, inter, cont_feats,
        Pint, Ptestg, Pitem, Ptag,
        comb_g, comb_beta, cont_W, cont_b, cont_g, cont_beta, out);
}

// Round 7
// 143.902 us; speedup vs baseline: 1.8499x; 1.0749x over previous
//
#include <hip/hip_runtime.h>
#include <hip/hip_bf16.h>

// Problem dims (fixed by the reference)
#define NTOK   (256 * 512)     // B*S tokens
#define N_USER 7442

using bf16 = __hip_bfloat16;
typedef float f32x4 __attribute__((ext_vector_type(4)));  // native vec for nontemporal builtin

static __device__ __forceinline__ float4 ld4(const float* p) {
    return *reinterpret_cast<const float4*>(p);
}
// bf16 pair unpack (little-endian: element at lower address = low 16 bits)
static __device__ __forceinline__ float bfl(unsigned u) {
    union { unsigned u; float f; } c; c.u = u << 16; return c.f;
}
static __device__ __forceinline__ float bfh(unsigned u) {
    union { unsigned u; float f; } c; c.u = u & 0xFFFF0000u; return c.f;
}
static __device__ __forceinline__ void st_nt4(float* p, float x, float y, float z, float w) {
    f32x4 v; v.x = x; v.y = y; v.z = z; v.w = w;
    __builtin_nontemporal_store(v, reinterpret_cast<f32x4*>(p));
}
// pack 4 f32 -> 4 bf16 (8B store)
static __device__ __forceinline__ void st_bf4(bf16* dst, float4 v) {
    union { bf16 h[4]; uint2 u; } pk;
    pk.h[0] = __float2bfloat16(v.x);
    pk.h[1] = __float2bfloat16(v.y);
    pk.h[2] = __float2bfloat16(v.z);
    pk.h[3] = __float2bfloat16(v.w);
    *reinterpret_cast<uint2*>(dst) = pk.u;
}

// ---- precompute geometry ----
// Wave->work mapping: each wave owns a row-slice and ALL 256 output columns
// (4 cols/lane) -> 4x fewer broadcast ds_reads than the column-sliced mapping;
// inner loop is VALU-bound (128 fmac vs 8 ds_read per 4-m step).
#define RS 32                 // rows/block, simple path (8 rows/wave)
#define RG 16                 // rows/block, graph path (4 rows/wave)
#define NB_TESTG 94           // ceil(1500/16)  (longest blocks first)
#define NB_ITEM  296          // ceil(9455/32)
#define NB_TAG   29           // ceil(913/32)
#define NB_INT   1            // 3 rows
#define NB_TOTAL (NB_TESTG + NB_ITEM + NB_TAG + NB_INT)

// Folded tables:
//   Pitem  = emb_item @ W2                       (bf16, 9455x256)
//   Ptag   = emb_tag  @ W3                       (bf16,  913x256)
//   Pint   = emb_int  @ W0                       (bf16,    3x256)
//   Ptestg = emb_test @ W1 + (graph_rows @ graph_W) @ W4 + comb_b + graph_b @ W4
__global__ __launch_bounds__(256) void precompute_kernel(
    const float* __restrict__ emb_int,  const float* __restrict__ emb_test,
    const float* __restrict__ emb_item, const float* __restrict__ emb_tag,
    const float* __restrict__ graph_tab, const float* __restrict__ graph_W,
    const float* __restrict__ graph_b,
    const float* __restrict__ comb_W,   const float* __restrict__ comb_b,
    bf16* __restrict__ Pint, bf16* __restrict__ Ptestg,
    bf16* __restrict__ Pitem, bf16* __restrict__ Ptag) {
    __shared__ float lds[8192];   // 32 KB
    const int tid  = threadIdx.x;
    const int w    = tid >> 6;
    const int lane = tid & 63;
    const int c    = lane * 4;    // this lane's 4 output columns
    const int b    = blockIdx.x;

    const float* W0 = comb_W;              // interaction
    const float* W1 = comb_W + 256 * 256;  // testId
    const float* W2 = comb_W + 512 * 256;  // itemId
    const float* W3 = comb_W + 768 * 256;  // tag
    const float* W4 = comb_W + 1024 * 256; // graph

    if (b < NB_TESTG) {
        // -------- graph+test fused path: wave owns 4 rows --------
        const int row0 = b * RG;
        const int nr   = min(RG, 1500 - row0);

        // A: stage graph rows (16 x 512 f32 = 32 KB)
        for (int i = tid; i < nr * 512; i += 256) {
            const int r = i >> 9, m = i & 511;
            lds[r * 512 + m] = graph_tab[(size_t)(N_USER - 1 + row0 + r) * 512 + m];
        }
        __syncthreads();

        // B: tmp = rows @ graph_W   (K = 512)
        float4 acc[4];
        #pragma unroll
        for (int r = 0; r < 4; ++r) acc[r] = float4{0.f, 0.f, 0.f, 0.f};
        for (int m = 0; m < 512; m += 4) {
            const float4 wv0 = ld4(graph_W + (m + 0) * 256 + c);
            const float4 wv1 = ld4(graph_W + (m + 1) * 256 + c);
            const float4 wv2 = ld4(graph_W + (m + 2) * 256 + c);
            const float4 wv3 = ld4(graph_W + (m + 3) * 256 + c);
            #pragma unroll
            for (int r = 0; r < 4; ++r) {
                const int rr = min(w * 4 + r, nr - 1);
                const float4 e = ld4(&lds[rr * 512 + m]);
                acc[r].x += e.x * wv0.x + e.y * wv1.x + e.z * wv2.x + e.w * wv3.x;
                acc[r].y += e.x * wv0.y + e.y * wv1.y + e.z * wv2.y + e.w * wv3.y;
                acc[r].z += e.x * wv0.z + e.y * wv1.z + e.z * wv2.z + e.w * wv3.z;
                acc[r].w += e.x * wv0.w + e.y * wv1.w + e.z * wv2.w + e.w * wv3.w;
            }
        }
        __syncthreads();   // all phase-B reads done before overwrite

        // tmp -> lds[0..4095]; emb_test rows -> lds[4096..8191]
        #pragma unroll
        for (int r = 0; r < 4; ++r)
            *reinterpret_cast<float4*>(&lds[(w * 4 + r) * 256 + c]) = acc[r];
        for (int i = tid; i < nr * 256; i += 256) {
            const int r = i >> 8, m = i & 255;
            lds[4096 + r * 256 + m] = emb_test[(size_t)(row0 + r) * 256 + m];
        }
        __syncthreads();

        // C: P = tmp @ W4 + test @ W1 (+ graph_b @ W4 + comb_b)
        float4 acc2[4];
        float4 bacc = float4{0.f, 0.f, 0.f, 0.f};
        #pragma unroll
        for (int r = 0; r < 4; ++r) acc2[r] = float4{0.f, 0.f, 0.f, 0.f};
        for (int m = 0; m < 256; m += 4) {
            const float4 w40 = ld4(W4 + (m + 0) * 256 + c);
            const float4 w41 = ld4(W4 + (m + 1) * 256 + c);
            const float4 w42 = ld4(W4 + (m + 2) * 256 + c);
            const float4 w43 = ld4(W4 + (m + 3) * 256 + c);
            const float4 w10 = ld4(W1 + (m + 0) * 256 + c);
            const float4 w11 = ld4(W1 + (m + 1) * 256 + c);
            const float4 w12 = ld4(W1 + (m + 2) * 256 + c);
            const float4 w13 = ld4(W1 + (m + 3) * 256 + c);
            const float gb0 = graph_b[m + 0], gb1 = graph_b[m + 1];
            const float gb2 = graph_b[m + 2], gb3 = graph_b[m + 3];
            bacc.x += gb0 * w40.x + gb1 * w41.x + gb2 * w42.x + gb3 * w43.x;
            bacc.y += gb0 * w40.y + gb1 * w41.y + gb2 * w42.y + gb3 * w43.y;
            bacc.z += gb0 * w40.z + gb1 * w41.z + gb2 * w42.z + gb3 * w43.z;
            bacc.w += gb0 * w40.w + gb1 * w41.w + gb2 * w42.w + gb3 * w43.w;
            #pragma unroll
            for (int r = 0; r < 4; ++r) {
                const int rr = min(w * 4 + r, nr - 1);
                const float4 tv = ld4(&lds[rr * 256 + m]);
                const float4 ev = ld4(&lds[4096 + rr * 256 + m]);
                acc2[r].x += tv.x * w40.x + tv.y * w41.x + tv.z * w42.x + tv.w * w43.x
                           + ev.x * w10.x + ev.y * w11.x + ev.z * w12.x + ev.w * w13.x;
                acc2[r].y += tv.x * w40.y + tv.y * w41.y + tv.z * w42.y + tv.w * w43.y
                           + ev.x * w10.y + ev.y * w11.y + ev.z * w12.y + ev.w * w13.y;
                acc2[r].z += tv.x * w40.z + tv.y * w41.z + tv.z * w42.z + tv.w * w43.z
                           + ev.x * w10.z + ev.y * w11.z + ev.z * w12.z + ev.w * w13.z;
                acc2[r].w += tv.x * w40.w + tv.y * w41.w + tv.z * w42.w + tv.w * w43.w
                           + ev.x * w10.w + ev.y * w11.w + ev.z * w12.w + ev.w * w13.w;
            }
        }
        const float4 cbv = ld4(comb_b + c);
        #pragma unroll
        for (int r = 0; r < 4; ++r) {
            const int row = w * 4 + r;
            if (row < nr) {
                float4 o;
                o.x = acc2[r].x + bacc.x + cbv.x;
                o.y = acc2[r].y + bacc.y + cbv.y;
                o.z = acc2[r].z + bacc.z + cbv.z;
                o.w = acc2[r].w + bacc.w + cbv.w;
                st_bf4(Ptestg + (size_t)(row0 + row) * 256 + c, o);
            }
        }
    } else {
        // -------- simple path: P = E @ W, K = 256; wave owns 8 rows --------
        const float* E; const float* W; bf16* P; int row0, R;
        const int sb = b - NB_TESTG;
        if (sb < NB_ITEM)               { E = emb_item; W = W2; P = Pitem; row0 = sb * RS;             R = 9455; }
        else if (sb < NB_ITEM + NB_TAG) { E = emb_tag;  W = W3; P = Ptag;  row0 = (sb - NB_ITEM) * RS; R = 913;  }
        else                            { E = emb_int;  W = W0; P = Pint;  row0 = 0;                   R = 3;    }
        const int nr = min(RS, R - row0);

        for (int i = tid; i < nr * 256; i += 256) {
            const int r = i >> 8, m = i & 255;
            lds[r * 256 + m] = E[(size_t)(row0 + r) * 256 + m];
        }
        __syncthreads();

        float4 acc[8];
        #pragma unroll
        for (int r = 0; r < 8; ++r) acc[r] = float4{0.f, 0.f, 0.f, 0.f};
        for (int m = 0; m < 256; m += 4) {
            const float4 wv0 = ld4(W + (m + 0) * 256 + c);
            const float4 wv1 = ld4(W + (m + 1) * 256 + c);
            const float4 wv2 = ld4(W + (m + 2) * 256 + c);
            const float4 wv3 = ld4(W + (m + 3) * 256 + c);
            #pragma unroll
            for (int r = 0; r < 8; ++r) {
                const int rr = min(w * 8 + r, nr - 1);
                const float4 e = ld4(&lds[rr * 256 + m]);
                acc[r].x += e.x * wv0.x + e.y * wv1.x + e.z * wv2.x + e.w * wv3.x;
                acc[r].y += e.x * wv0.y + e.y * wv1.y + e.z * wv2.y + e.w * wv3.y;
                acc[r].z += e.x * wv0.z + e.y * wv1.z + e.z * wv2.z + e.w * wv3.z;
                acc[r].w += e.x * wv0.w + e.y * wv1.w + e.z * wv2.w + e.w * wv3.w;
            }
        }
        #pragma unroll
        for (int r = 0; r < 8; ++r) {
            const int row = w * 8 + r;
            if (row < nr)
                st_bf4(P + (size_t)(row0 + row) * 256 + c, acc[r]);
        }
    }
}

// 2048 blocks x 256 threads; each wave handles 16 consecutive tokens.
// Wave-invariant params hoisted into registers before the token loop.
__global__ __launch_bounds__(256) void main_kernel(
    const int* __restrict__ testId, const int* __restrict__ itemId,
    const int* __restrict__ tagId,  const int* __restrict__ inter,
    const float* __restrict__ cont_feats,
    const bf16* __restrict__ Pint, const bf16* __restrict__ Ptestg,
    const bf16* __restrict__ Pitem, const bf16* __restrict__ Ptag,
    const float* __restrict__ comb_g, const float* __restrict__ comb_beta,
    const float* __restrict__ cont_W, const float* __restrict__ cont_b,
    const float* __restrict__ cont_g, const float* __restrict__ cont_beta,
    float* __restrict__ out) {
    const int wid  = blockIdx.x * 4 + (threadIdx.x >> 6);
    const int lane = threadIdx.x & 63;
    const int c    = lane * 4;

    // hoisted wave-invariant parameters (8 x float4 = 32 VGPRs)
    const float4 g4  = ld4(comb_g + c);
    const float4 b4  = ld4(comb_beta + c);
    const float4 w0  = ld4(cont_W + 0 * 256 + c);
    const float4 w1  = ld4(cont_W + 1 * 256 + c);
    const float4 w2  = ld4(cont_W + 2 * 256 + c);
    const float4 cb  = ld4(cont_b + c);
    const float4 g42 = ld4(cont_g + c);
    const float4 b42 = ld4(cont_beta + c);

    const int t0 = wid * 16;
    #pragma unroll 2
    for (int k = 0; k < 16; ++k) {
        const int t = t0 + k;
        const int ti = testId[t];
        const int ii = itemId[t];
        const int tg = tagId[t];
        const int iv = inter[t];

        // ---- cate path: 4 bf16 gathers (Ptestg carries bias) ----
        const uint2 u0 = *reinterpret_cast<const uint2*>(Pint   + iv * 256 + c);
        const uint2 u1 = *reinterpret_cast<const uint2*>(Ptestg + (size_t)ti * 256 + c);
        const uint2 u2 = *reinterpret_cast<const uint2*>(Pitem  + (size_t)ii * 256 + c);
        const uint2 u3 = *reinterpret_cast<const uint2*>(Ptag   + (size_t)tg * 256 + c);
        float vx = bfl(u0.x) + bfl(u1.x) + bfl(u2.x) + bfl(u3.x);
        float vy = bfh(u0.x) + bfh(u1.x) + bfh(u2.x) + bfh(u3.x);
        float vz = bfl(u0.y) + bfl(u1.y) + bfl(u2.y) + bfl(u3.y);
        float vw = bfh(u0.y) + bfh(u1.y) + bfh(u2.y) + bfh(u3.y);

        float s  = vx + vy + vz + vw;
        float ss = vx * vx + vy * vy + vz * vz + vw * vw;
        #pragma unroll
        for (int off = 32; off >= 1; off >>= 1) {
            s  += __shfl_xor(s,  off, 64);
            ss += __shfl_xor(ss, off, 64);
        }
        const float mu  = s * (1.f / 256.f);
        const float var = ss * (1.f / 256.f) - mu * mu;
        const float inv = rsqrtf(var + 1e-5f);

        float* po = out + (size_t)t * 512;
        st_nt4(po + c,
               (vx - mu) * inv * g4.x + b4.x,
               (vy - mu) * inv * g4.y + b4.y,
               (vz - mu) * inv * g4.z + b4.z,
               (vw - mu) * inv * g4.w + b4.w);

        // ---- cont path: [3] @ cont_W[3][256] + LN ----
        const float c0 = cont_feats[t * 3 + 0];
        const float c1 = cont_feats[t * 3 + 1];
        const float c2 = cont_feats[t * 3 + 2];
        float ux = c0 * w0.x + c1 * w1.x + c2 * w2.x + cb.x;
        float uy = c0 * w0.y + c1 * w1.y + c2 * w2.y + cb.y;
        float uz = c0 * w0.z + c1 * w1.z + c2 * w2.z + cb.z;
        float uw = c0 * w0.w + c1 * w1.w + c2 * w2.w + cb.w;

        float s2  = ux + uy + uz + uw;
        float ss2 = ux * ux + uy * uy + uz * uz + uw * uw;
        #pragma unroll
        for (int off = 32; off >= 1; off >>= 1) {
            s2  += __shfl_xor(s2,  off, 64);
            ss2 += __shfl_xor(ss2, off, 64);
        }
        const float mu2  = s2 * (1.f / 256.f);
        const float var2 = ss2 * (1.f / 256.f) - mu2 * mu2;
        const float inv2 = rsqrtf(var2 + 1e-5f);

        st_nt4(po + 256 + c,
               (ux - mu2) * inv2 * g42.x + b42.x,
               (uy - mu2) * inv2 * g42.y + b42.y,
               (uz - mu2) * inv2 * g42.z + b42.z,
               (uw - mu2) * inv2 * g42.w + b42.w);
    }
}

extern "C" void kernel_launch(void* const* d_in, const int* in_sizes, int n_in,
                              void* d_out, int out_size, void* d_ws, size_t ws_size,
                              hipStream_t stream) {
    const int*   testId     = (const int*)d_in[0];
    const int*   itemId     = (const int*)d_in[1];
    const int*   tagId      = (const int*)d_in[2];
    const float* cont_feats = (const float*)d_in[3];
    const int*   inter      = (const int*)d_in[4];
    const float* emb_int    = (const float*)d_in[5];
    const float* emb_test   = (const float*)d_in[6];
    const float* emb_item   = (const float*)d_in[7];
    const float* emb_tag    = (const float*)d_in[8];
    const float* graph_tab  = (const float*)d_in[9];
    const float* graph_W    = (const float*)d_in[10];
    const float* graph_b    = (const float*)d_in[11];
    const float* comb_W     = (const float*)d_in[12];
    const float* comb_b     = (const float*)d_in[13];
    const float* comb_g     = (const float*)d_in[14];
    const float* comb_beta  = (const float*)d_in[15];
    const float* cont_W     = (const float*)d_in[16];
    const float* cont_b     = (const float*)d_in[17];
    const float* cont_g     = (const float*)d_in[18];
    const float* cont_beta  = (const float*)d_in[19];
    float* out              = (float*)d_out;

    // Workspace: bf16 tables, each offset 256-element aligned. ~6.1 MB total.
    bf16* ws     = (bf16*)d_ws;
    bf16* Pitem  = ws;                         // 9455*256
    bf16* Ptestg = Pitem  + 9455 * 256;        // 1500*256 (test + graph + bias fused)
    bf16* Ptag   = Ptestg + 1500 * 256;        //  913*256
    bf16* Pint   = Ptag   +  913 * 256;        //    3*256

    precompute_kernel<<<NB_TOTAL, 256, 0, stream>>>(
        emb_int, emb_test, emb_item, emb_tag, graph_tab, graph_W, graph_b,
        comb_W, comb_b, Pint, Ptestg, Pitem, Ptag);

    // 2048 blocks x 4 waves; 16 tokens per wave.
    main_kernel<<<NTOK / (4 * 16), 256, 0, stream>>>(
        testId, itemId, tagId, inter, cont_feats,
        Pint, Ptestg, Pitem, Ptag,
        comb_g, comb_beta, cont_W, cont_b, cont_g, cont_beta, out);
}